// Round 10
// baseline (835.820 us; speedup 1.0000x reference)
//
#include <hip/hip_runtime.h>
#include <hip/hip_bf16.h>
#include <cstdint>

#define B_ 512
#define S_ 512
#define V_ 5000
#define E_ 100
#define HD_ 64
#define T_ 25
#define START_ 1
#define STOP_ 2

typedef __attribute__((ext_vector_type(8))) short short8;
typedef __attribute__((ext_vector_type(4))) float f32x4;
typedef __attribute__((ext_vector_type(8))) _Float16 f16x8;

__device__ inline float sigm(float x) { return 1.0f / (1.0f + __expf(-x)); }
__device__ inline float tanh_(float x) { return 1.0f - 2.0f / (1.0f + __expf(2.0f * x)); }

__device__ inline f32x4 mm16(f16x8 a, f16x8 b, f32x4 c) {
  return __builtin_amdgcn_mfma_f32_16x16x32_f16(a, b, c, 0, 0, 0);
}

// raw barrier: lgkm-only drain. vmcnt NOT drained -> emb prefetch and feat
// stores stay in flight across the barrier (r6's 2000cyc/step stall was the
// vmcnt(0) drain hipcc emits before s_barrier for __syncthreads).
#define RAW_BAR() asm volatile("s_waitcnt lgkmcnt(0)\n\ts_barrier" ::: "memory")

// ---------------- prep: Wcomb[d][256][192] f16 = [Whh | Wih | 0] -------------
__global__ __launch_bounds__(256) void k_prep_w(const float* __restrict__ Whh_f,
                                                const float* __restrict__ Wih_f,
                                                const float* __restrict__ Whh_b,
                                                const float* __restrict__ Wih_b,
                                                _Float16* __restrict__ Wcomb) {
  int idx = blockIdx.x * 256 + threadIdx.x;
  if (idx >= 2 * 256 * 192) return;
  int d = idx / (256 * 192);
  int rem = idx % (256 * 192);
  int u = rem / 192, k = rem % 192;
  const float* Whh = d ? Whh_b : Whh_f;
  const float* Wih = d ? Wih_b : Wih_f;
  float v = (k < HD_) ? Whh[u * HD_ + k]
                      : ((k < HD_ + E_) ? Wih[u * E_ + (k - HD_)] : 0.f);
  Wcomb[idx] = (_Float16)v;
}

// ---------------- prep: embP[V][112] f16 (cols >= 100 zero) -------------------
__global__ __launch_bounds__(256) void k_prep_e(const float* __restrict__ embed,
                                                _Float16* __restrict__ embP) {
  int idx = blockIdx.x * 256 + threadIdx.x;
  if (idx >= V_ * 112) return;
  int v = idx / 112, e = idx % 112;
  embP[idx] = (e < E_) ? (_Float16)embed[v * E_ + e] : (_Float16)0.f;
}

// ---------------- prep: WoutPad[32][128] bf16 (rows >= 25 zero) ---------------
__global__ __launch_bounds__(256) void k_prep_o(const float* __restrict__ Wout,
                                                __hip_bfloat16* __restrict__ WoutP) {
  int idx = blockIdx.x * 256 + threadIdx.x;
  if (idx < 32 * 128) {
    int r = idx >> 7, c = idx & 127;
    float v = (r < T_) ? Wout[r * 128 + c] : 0.f;
    WoutP[idx] = __float2bfloat16(v);
  }
}

// ---------------- K2: BiLSTM recurrence via MFMA + raw barriers ---------------
// r6-verbatim structure (correctness-proven) with the single fix: the per-step
// __syncthreads -> raw lgkm-only barrier. Gang of 16 seqs, 4 waves; wave w owns
// units 16w..16w+15 x 4 gates; Z = [H|emb].Wcomb^T via 24 mfma/wave (K=192).
// B-frags live in AGPRs (MFMA reads them natively - no accvgpr_read tax).
__global__ __launch_bounds__(256, 1) void k_lstm(
    const int* __restrict__ sentences,
    const _Float16* __restrict__ embP,     // [V][112]
    const _Float16* __restrict__ Wcomb,    // [2][256][192]
    const float* __restrict__ bih_f, const float* __restrict__ bhh_f,
    const float* __restrict__ bih_b, const float* __restrict__ bhh_b,
    const float* __restrict__ h0, const float* __restrict__ c0,
    __hip_bfloat16* __restrict__ feat) {
  int tid = threadIdx.x;
  int w = tid >> 6, l = tid & 63;
  int row = tid >> 4, tr = tid & 15;       // staging role: 16 thr per seq-row
  int grp = blockIdx.x & 31, d = blockIdx.x >> 5;
  int sbase = grp * 16;
  const float* bih = d ? bih_b : bih_f;
  const float* bhh = d ? bhh_b : bhh_f;

  __shared__ __align__(16) _Float16 Hs[2][16][72];
  __shared__ __align__(16) _Float16 Ae[2][16][136];

  int mrow = l & 15, kg = l >> 4;
  int ucol = w * 16 + mrow;                // unit this lane owns
  int r0 = kg * 4;                         // lane's first seq row (D-layout)

  f16x8 Bf[4][6];
  const _Float16* Wd = Wcomb + (size_t)d * 256 * 192;
#pragma unroll
  for (int g = 0; g < 4; g++) {
    const _Float16* rp = Wd + (size_t)(g * 64 + ucol) * 192;
#pragma unroll
    for (int kt = 0; kt < 6; kt++)
      Bf[g][kt] = *(const f16x8*)(rp + kt * 32 + kg * 8);
  }
  float bg[4];
#pragma unroll
  for (int g = 0; g < 4; g++) {
    int u = g * 64 + ucol;
    bg[g] = bih[u] + bhh[u];
  }
  float cc[4];
#pragma unroll
  for (int q = 0; q < 4; q++)
    cc[q] = c0[(size_t)(d * B_ + sbase + r0 + q) * HD_ + ucol];

  for (int idx = tid; idx < 16 * HD_; idx += 256)
    Hs[0][idx >> 6][idx & 63] =
        (_Float16)h0[(size_t)(d * B_ + sbase + (idx >> 6)) * HD_ + (idx & 63)];
  for (int idx = tid; idx < 2 * 16 * 24; idx += 256) {
    int bsel = idx / (16 * 24);
    int rem = idx % (16 * 24);
    Ae[bsel][rem / 24][112 + rem % 24] = (_Float16)0.f;
  }

  const int* sent_row = sentences + (size_t)(sbase + row) * S_;
  int tt0 = d ? (S_ - 1) : 0, stp = d ? -1 : 1;
  int tok0 = sent_row[tt0];
  if (tr < 14) {
    uint4 g0 = ((const uint4*)embP)[(size_t)tok0 * 14 + tr];
    *(uint4*)(&Ae[0][row][tr * 8]) = g0;
  }
  int tokN = sent_row[tt0 + stp];          // token for t=1
  __syncthreads();                          // once, pre-loop (full drain fine)

  for (int t = 0; t < S_; ++t) {
    int cur = t & 1, nxt = cur ^ 1;
    int tt = tt0 + stp * t;
    // prefetch emb(t+1) into regs: issued first so the later counted-vmcnt
    // wait (before the Ae write) only covers this load, not the feat stores.
    uint4 gv;
    bool havegv = (t + 1 < S_) && (tr < 14);
    if (havegv) gv = ((const uint4*)embP)[(size_t)tokN * 14 + tr];
    int tokN2 = tokN;
    if (t + 2 < S_) tokN2 = sent_row[tt + 2 * stp];

    f16x8 Ah0 = *(const f16x8*)(&Hs[cur][mrow][kg * 8]);
    f16x8 Ah1 = *(const f16x8*)(&Hs[cur][mrow][32 + kg * 8]);
    f16x8 Ae0 = *(const f16x8*)(&Ae[cur][mrow][kg * 8]);
    f16x8 Ae1 = *(const f16x8*)(&Ae[cur][mrow][32 + kg * 8]);
    f16x8 Ae2 = *(const f16x8*)(&Ae[cur][mrow][64 + kg * 8]);
    f16x8 Ae3 = *(const f16x8*)(&Ae[cur][mrow][96 + kg * 8]);

    f32x4 acc[4];
#pragma unroll
    for (int g = 0; g < 4; g++) {
      acc[g] = (f32x4){bg[g], bg[g], bg[g], bg[g]};
      acc[g] = mm16(Ah0, Bf[g][0], acc[g]);
      acc[g] = mm16(Ah1, Bf[g][1], acc[g]);
      acc[g] = mm16(Ae0, Bf[g][2], acc[g]);
      acc[g] = mm16(Ae1, Bf[g][3], acc[g]);
      acc[g] = mm16(Ae2, Bf[g][4], acc[g]);
      acc[g] = mm16(Ae3, Bf[g][5], acc[g]);
    }
#pragma unroll
    for (int q = 0; q < 4; q++) {
      float zi = acc[0][q], zf = acc[1][q], zg = acc[2][q], zo = acc[3][q];
      float c2 = sigm(zf) * cc[q] + sigm(zi) * tanh_(zg);
      cc[q] = c2;
      float hh = sigm(zo) * tanh_(c2);
      Hs[nxt][r0 + q][ucol] = (_Float16)hh;
      feat[(((size_t)(sbase + r0 + q)) * S_ + tt) * 128 + d * 64 + ucol] =
          __float2bfloat16(hh);
    }
    if (havegv) *(uint4*)(&Ae[nxt][row][tr * 8]) = gv;  // counted vmcnt wait
    tokN = tokN2;
    RAW_BAR();                              // lgkm-only: stores stay in flight
  }
}

// ---------------- K3: logits = feat . WoutP^T + bout via MFMA -----------------
__global__ __launch_bounds__(256) void k_logits(const __hip_bfloat16* __restrict__ feat,
                                                const __hip_bfloat16* __restrict__ WoutP,
                                                const float* __restrict__ bout,
                                                float* __restrict__ logits) {
  int w = threadIdx.x >> 6, l = threadIdx.x & 63;
  size_t r0 = ((size_t)blockIdx.x * 4 + w) * 16;
  int mrow = l & 15, kg = l >> 4;
  short8 bfr[2][4];
#pragma unroll
  for (int nt = 0; nt < 2; nt++) {
    int n = nt * 16 + mrow;
#pragma unroll
    for (int kb = 0; kb < 4; kb++)
      bfr[nt][kb] = *(const short8*)(WoutP + n * 128 + kb * 32 + kg * 8);
  }
  f32x4 acc[2];
#pragma unroll
  for (int nt = 0; nt < 2; nt++) {
    int col = nt * 16 + mrow;
    float bb = (col < T_) ? bout[col] : 0.f;
    acc[nt] = (f32x4){bb, bb, bb, bb};
  }
#pragma unroll
  for (int kb = 0; kb < 4; kb++) {
    short8 a = *(const short8*)(feat + (r0 + mrow) * 128 + kb * 32 + kg * 8);
    acc[0] = __builtin_amdgcn_mfma_f32_16x16x32_bf16(a, bfr[0][kb], acc[0], 0, 0, 0);
    acc[1] = __builtin_amdgcn_mfma_f32_16x16x32_bf16(a, bfr[1][kb], acc[1], 0, 0, 0);
  }
#pragma unroll
  for (int nt = 0; nt < 2; nt++) {
    int col = nt * 16 + mrow;
    if (col < T_) {
#pragma unroll
      for (int q = 0; q < 4; q++) {
        int rowq = kg * 4 + q;
        logits[(r0 + rowq) * T_ + col] = acc[nt][q];
      }
    }
  }
}

// ---------------- K4: CRF forward, 1 wave = 1 batch elem (r5-proven form) ----
__global__ __launch_bounds__(64) void k_crf(const float* __restrict__ logits,
                                            const float* __restrict__ trans,
                                            float* __restrict__ totals) {
  int j = threadIdx.x;
  int b = blockIdx.x;
  bool act = j < T_;
  __shared__ __align__(16) float qS[32];
  float Ecol[T_];
#pragma unroll
  for (int i = 0; i < T_; i++)
    Ecol[i] = act ? __expf(trans[i * T_ + j]) : 0.f;
  if (j >= T_ && j < 32) qS[j] = 0.f;
  float tstop = act ? trans[j * T_ + STOP_] : 0.f;
  float prev = act ? 0.f : -INFINITY;
  const float* lg = logits + (size_t)b * S_ * T_;
  float ltn = act ? lg[j] : 0.f;
  asm volatile("s_waitcnt lgkmcnt(0)" ::: "memory");
  for (int t = 0; t < S_; t++) {
    float lt = ltn;
    if (t + 1 < S_) ltn = act ? lg[(size_t)(t + 1) * T_ + j] : 0.f;
    float m = __builtin_bit_cast(float,
        __builtin_amdgcn_readfirstlane(__builtin_bit_cast(int, prev)));
    float q = __expf(prev - m);
    if (act) qS[j] = q;
    asm volatile("s_waitcnt lgkmcnt(0)" ::: "memory");
    const float4* q4 = (const float4*)qS;
    float4 qv0 = q4[0], qv1 = q4[1], qv2 = q4[2], qv3 = q4[3];
    float4 qv4 = q4[4], qv5 = q4[5], qv6 = q4[6];
    float s0, s1, s2, s3;
    s0 = qv0.x * Ecol[0];  s1 = qv0.y * Ecol[1];
    s2 = qv0.z * Ecol[2];  s3 = qv0.w * Ecol[3];
    s0 += qv1.x * Ecol[4];  s1 += qv1.y * Ecol[5];
    s2 += qv1.z * Ecol[6];  s3 += qv1.w * Ecol[7];
    s0 += qv2.x * Ecol[8];  s1 += qv2.y * Ecol[9];
    s2 += qv2.z * Ecol[10]; s3 += qv2.w * Ecol[11];
    s0 += qv3.x * Ecol[12]; s1 += qv3.y * Ecol[13];
    s2 += qv3.z * Ecol[14]; s3 += qv3.w * Ecol[15];
    s0 += qv4.x * Ecol[16]; s1 += qv4.y * Ecol[17];
    s2 += qv4.z * Ecol[18]; s3 += qv4.w * Ecol[19];
    s0 += qv5.x * Ecol[20]; s1 += qv5.y * Ecol[21];
    s2 += qv5.z * Ecol[22]; s3 += qv5.w * Ecol[23];
    s0 += qv6.x * Ecol[24];
    float s = (s0 + s1) + (s2 + s3);
    prev = lt + m + __logf(s);
    if (!act) prev = -INFINITY;
  }
  float v = prev + tstop;
  float m = v;
#pragma unroll
  for (int off = 32; off > 0; off >>= 1)
    m = fmaxf(m, __shfl_xor(m, off, 64));
  float e = __expf(v - m);
#pragma unroll
  for (int off = 32; off > 0; off >>= 1)
    e += __shfl_xor(e, off, 64);
  if (j == 0) totals[b] = m + __logf(e);
}

// ---------------- K5: gold path score per b ----------------------------------
__global__ __launch_bounds__(256) void k_real(const float* __restrict__ logits,
                                              const int* __restrict__ tags,
                                              const float* __restrict__ trans,
                                              float* __restrict__ reals) {
  __shared__ float red[256];
  int b = blockIdx.x;
  float acc = 0.f;
  for (int s = threadIdx.x; s < S_; s += 256) {
    int tg = tags[(size_t)b * S_ + s];
    int pv = (s == 0) ? START_ : tags[(size_t)b * S_ + s - 1];
    acc += logits[((size_t)b * S_ + s) * T_ + tg] + trans[pv * T_ + tg];
  }
  red[threadIdx.x] = acc;
  __syncthreads();
  for (int off = 128; off > 0; off >>= 1) {
    if (threadIdx.x < off) red[threadIdx.x] += red[threadIdx.x + off];
    __syncthreads();
  }
  if (threadIdx.x == 0)
    reals[b] = red[0] + trans[tags[(size_t)b * S_ + S_ - 1] * T_ + STOP_];
}

// ---------------- K6: out = sum_b totals - reals -----------------------------
__global__ __launch_bounds__(256) void k_final(const float* __restrict__ totals,
                                               const float* __restrict__ reals,
                                               float* __restrict__ out) {
  __shared__ float red[256];
  float acc = 0.f;
  for (int b = threadIdx.x; b < B_; b += 256) acc += totals[b] - reals[b];
  red[threadIdx.x] = acc;
  __syncthreads();
  for (int off = 128; off > 0; off >>= 1) {
    if (threadIdx.x < off) red[threadIdx.x] += red[threadIdx.x + off];
    __syncthreads();
  }
  if (threadIdx.x == 0) out[0] = red[0];
}

// ws: feat(bf16) 67,108,864 | logits 26,214,400 | WoutP 8,192 |
//     Wcomb 196,608 | embP 1,120,000 | totals 2,048 | reals 2,048
extern "C" void kernel_launch(void* const* d_in, const int* in_sizes, int n_in,
                              void* d_out, int out_size, void* d_ws, size_t ws_size,
                              hipStream_t stream) {
  const int*   sentences = (const int*)d_in[0];
  const int*   tags  = (const int*)d_in[1];
  const float* embed = (const float*)d_in[2];
  const float* Wih_f = (const float*)d_in[3];
  const float* Whh_f = (const float*)d_in[4];
  const float* bih_f = (const float*)d_in[5];
  const float* bhh_f = (const float*)d_in[6];
  const float* Wih_b = (const float*)d_in[7];
  const float* Whh_b = (const float*)d_in[8];
  const float* bih_b = (const float*)d_in[9];
  const float* bhh_b = (const float*)d_in[10];
  const float* h0    = (const float*)d_in[11];
  const float* c0    = (const float*)d_in[12];
  const float* Wout  = (const float*)d_in[13];
  const float* bout  = (const float*)d_in[14];
  const float* trans = (const float*)d_in[15];

  char* ws = (char*)d_ws;
  __hip_bfloat16* feat  = (__hip_bfloat16*)(ws);
  float* logits         = (float*)(ws + 67108864);
  __hip_bfloat16* WoutP = (__hip_bfloat16*)(ws + 67108864 + 26214400);
  _Float16* Wcomb       = (_Float16*)(ws + 67108864 + 26214400 + 8192);
  _Float16* embP        = (_Float16*)(ws + 67108864 + 26214400 + 8192 + 196608);
  float* totals         = (float*)(ws + 67108864 + 26214400 + 8192 + 196608 + 1120000);
  float* reals          = totals + B_;
  float* out            = (float*)d_out;

  k_prep_w<<<384, 256, 0, stream>>>(Whh_f, Wih_f, Whh_b, Wih_b, Wcomb);
  k_prep_e<<<2188, 256, 0, stream>>>(embed, embP);
  k_prep_o<<<16, 256, 0, stream>>>(Wout, WoutP);
  k_lstm<<<64, 256, 0, stream>>>(sentences, embP, Wcomb,
                                 bih_f, bhh_f, bih_b, bhh_b, h0, c0, feat);
  k_logits<<<4096, 256, 0, stream>>>(feat, WoutP, bout, logits);
  k_crf<<<512, 64, 0, stream>>>(logits, trans, totals);
  k_real<<<512, 256, 0, stream>>>(logits, tags, trans, reals);
  k_final<<<1, 256, 0, stream>>>(totals, reals, out);
}

// Round 11
// 556.554 us; speedup vs baseline: 1.5018x; 1.5018x over previous
//
#include <hip/hip_runtime.h>
#include <hip/hip_bf16.h>
#include <cstdint>

#define B_ 512
#define S_ 512
#define V_ 5000
#define E_ 100
#define HD_ 64
#define T_ 25
#define START_ 1
#define STOP_ 2

typedef _Float16 half2_t __attribute__((ext_vector_type(2)));
typedef __attribute__((ext_vector_type(8))) short short8;
typedef __attribute__((ext_vector_type(4))) float f32x4;

#if __has_builtin(__builtin_amdgcn_fdot2)
__device__ inline float dot2(uint32_t a, uint32_t b, float c) {
  return __builtin_amdgcn_fdot2(__builtin_bit_cast(half2_t, a),
                                __builtin_bit_cast(half2_t, b), c, false);
}
#else
__device__ inline float dot2(uint32_t a, uint32_t b, float c) {
  half2_t ha = __builtin_bit_cast(half2_t, a);
  half2_t hb = __builtin_bit_cast(half2_t, b);
  return c + (float)ha[0] * (float)hb[0] + (float)ha[1] * (float)hb[1];
}
#endif

__device__ inline float sigm(float x) { return 1.0f / (1.0f + __expf(-x)); }
__device__ inline float tanh_(float x) { return 1.0f - 2.0f / (1.0f + __expf(2.0f * x)); }

// ---------------- K1: P[v][j*4+g] = embed[v] . Wih[g*64+j], per dir ----------
// (r3-exact) k_lstm lane j loads float4 = (x_i,x_f,x_g,x_o) for hidden j.
__global__ __launch_bounds__(256) void k_proj(const float* __restrict__ embed,
                                              const float* __restrict__ Wf,
                                              const float* __restrict__ Wb,
                                              float* __restrict__ Pf,
                                              float* __restrict__ Pb) {
  __shared__ __align__(16) float embS[16 * E_];
  int v0 = blockIdx.x * 16;
  const float* Wih = blockIdx.y ? Wb : Wf;
  float* P = blockIdx.y ? Pb : Pf;
  int nv = V_ - v0; if (nv > 16) nv = 16;
  for (int idx = threadIdx.x; idx < nv * E_; idx += 256)
    embS[idx] = embed[v0 * E_ + idx];
  __syncthreads();
  int u = threadIdx.x;
  float acc[16];
#pragma unroll
  for (int i = 0; i < 16; i++) acc[i] = 0.f;
  const float4* W4 = (const float4*)(Wih + u * E_);
  const float4* e4 = (const float4*)embS;
#pragma unroll 5
  for (int q = 0; q < 25; q++) {
    float4 w = W4[q];
#pragma unroll
    for (int vi = 0; vi < 16; vi++) {
      float4 e = e4[vi * 25 + q];
      acc[vi] += w.x * e.x + w.y * e.y + w.z * e.z + w.w * e.w;
    }
  }
  int pk = (u & 63) * 4 + (u >> 6);   // hidden j -> float4 slot, gate -> comp
  for (int vi = 0; vi < nv; vi++)
    P[(size_t)(v0 + vi) * 256 + pk] = acc[vi];
}

// ---------------- K1b: WoutPad[32][128] bf16 (rows >= 25 zero) ----------------
__global__ __launch_bounds__(256) void k_prep(const float* __restrict__ Wout,
                                              __hip_bfloat16* __restrict__ WoutP) {
  int idx = blockIdx.x * 256 + threadIdx.x;
  if (idx < 32 * 128) {
    int r = idx >> 7, c = idx & 127;
    float v = (r < T_) ? Wout[r * 128 + c] : 0.f;
    WoutP[idx] = __float2bfloat16(v);
  }
}

// ---------------- K2: BiLSTM: r3 champion, byte-for-byte ----------------------
// 1 wave = 1 seq, no barriers; lane j owns hidden unit j (4 gate rows of Whh
// as f16 pairs); h broadcast via wave-synchronous LDS. Benched 349us twice.
__global__ __launch_bounds__(64, 1) void k_lstm(
    const int* __restrict__ sentences,
    const float* __restrict__ Pf, const float* __restrict__ Pb,
    const float* __restrict__ Whh_f, const float* __restrict__ Whh_b,
    const float* __restrict__ bih_f, const float* __restrict__ bhh_f,
    const float* __restrict__ bih_b, const float* __restrict__ bhh_b,
    const float* __restrict__ h0, const float* __restrict__ c0,
    __hip_bfloat16* __restrict__ feat) {
  int j = threadIdx.x;                 // 0..63 = hidden unit
  int seq = blockIdx.x;                // 0..1023
  int be = seq & (B_ - 1);
  int d = seq >> 9;                    // 0 fwd, 1 bwd
  const float* P   = d ? Pb : Pf;
  const float* Whh = d ? Whh_b : Whh_f;
  const float* bih = d ? bih_b : bih_f;
  const float* bhh = d ? bhh_b : bhh_f;

  __shared__ __align__(16) uint32_t hS[32];   // 64 f16 h values

  uint32_t wp[4][32];
  float bg[4];
#pragma unroll
  for (int g = 0; g < 4; g++) {
    int u = g * 64 + j;
    const float4* rp = (const float4*)(Whh + (size_t)u * HD_);
#pragma unroll
    for (int q = 0; q < 16; q++) {
      float4 a = rp[q];
      union { _Float16 h[2]; uint32_t u32; } p0, p1;
      p0.h[0] = (_Float16)a.x; p0.h[1] = (_Float16)a.y;
      p1.h[0] = (_Float16)a.z; p1.h[1] = (_Float16)a.w;
      wp[g][2 * q] = p0.u32; wp[g][2 * q + 1] = p1.u32;
    }
    bg[g] = bih[u] + bhh[u];
  }
  float c = c0[(d * B_ + be) * HD_ + j];
  ((_Float16*)hS)[j] = (_Float16)h0[(d * B_ + be) * HD_ + j];
  asm volatile("s_waitcnt lgkmcnt(0)" ::: "memory");

  const int* sent = sentences + (size_t)be * S_;
  int tt0 = d ? (S_ - 1) : 0;
  int stp = d ? -1 : 1;
  int tok1 = sent[tt0];
  const float4* P4 = (const float4*)P;
  float4 x = P4[(size_t)tok1 * 64 + j];
  tok1 = sent[tt0 + stp];
  const uint4* hS4 = (const uint4*)hS;

  for (int t = 0; t < S_; t++) {
    int tt = tt0 + stp * t;
    float4 xn = x;
    if (t + 1 < S_) xn = P4[(size_t)tok1 * 64 + j];
    int tok2 = tok1;
    if (t + 2 < S_) tok2 = sent[tt + 2 * stp];

    float a0 = 0.f, a1 = 0.f, a2 = 0.f, a3 = 0.f;  // even-kp accs
    float b0 = 0.f, b1 = 0.f, b2 = 0.f, b3 = 0.f;  // odd-kp accs
#pragma unroll
    for (int q = 0; q < 8; q++) {
      uint4 hv = hS4[q];
      int kp = 4 * q;
      a0 = dot2(wp[0][kp], hv.x, a0); b0 = dot2(wp[0][kp + 1], hv.y, b0);
      a0 = dot2(wp[0][kp + 2], hv.z, a0); b0 = dot2(wp[0][kp + 3], hv.w, b0);
      a1 = dot2(wp[1][kp], hv.x, a1); b1 = dot2(wp[1][kp + 1], hv.y, b1);
      a1 = dot2(wp[1][kp + 2], hv.z, a1); b1 = dot2(wp[1][kp + 3], hv.w, b1);
      a2 = dot2(wp[2][kp], hv.x, a2); b2 = dot2(wp[2][kp + 1], hv.y, b2);
      a2 = dot2(wp[2][kp + 2], hv.z, a2); b2 = dot2(wp[2][kp + 3], hv.w, b2);
      a3 = dot2(wp[3][kp], hv.x, a3); b3 = dot2(wp[3][kp + 1], hv.y, b3);
      a3 = dot2(wp[3][kp + 2], hv.z, a3); b3 = dot2(wp[3][kp + 3], hv.w, b3);
    }
    float zi = a0 + b0 + bg[0] + x.x;
    float zf = a1 + b1 + bg[1] + x.y;
    float zg = a2 + b2 + bg[2] + x.z;
    float zo = a3 + b3 + bg[3] + x.w;
    c = sigm(zf) * c + sigm(zi) * tanh_(zg);
    float hh = sigm(zo) * tanh_(c);
    feat[((size_t)be * S_ + tt) * 128 + d * 64 + j] = __float2bfloat16(hh);
    ((_Float16*)hS)[j] = (_Float16)hh;
    asm volatile("s_waitcnt lgkmcnt(0)" ::: "memory");
    x = xn;
    tok1 = tok2;
  }
}

// ---------------- K3: logits via MFMA, 32 rows/wave (B-frag reuse) ------------
__global__ __launch_bounds__(256) void k_logits(const __hip_bfloat16* __restrict__ feat,
                                                const __hip_bfloat16* __restrict__ WoutP,
                                                const float* __restrict__ bout,
                                                float* __restrict__ logits) {
  int w = threadIdx.x >> 6, l = threadIdx.x & 63;
  size_t r0 = ((size_t)blockIdx.x * 4 + w) * 32;
  int mrow = l & 15, kg = l >> 4;
  short8 bfr[2][4];
#pragma unroll
  for (int nt = 0; nt < 2; nt++) {
    int n = nt * 16 + mrow;
#pragma unroll
    for (int kb = 0; kb < 4; kb++)
      bfr[nt][kb] = *(const short8*)(WoutP + n * 128 + kb * 32 + kg * 8);
  }
  f32x4 acc[2][2];
  float bb[2];
#pragma unroll
  for (int nt = 0; nt < 2; nt++) {
    int col = nt * 16 + mrow;
    bb[nt] = (col < T_) ? bout[col] : 0.f;
  }
#pragma unroll
  for (int mt = 0; mt < 2; mt++)
#pragma unroll
    for (int nt = 0; nt < 2; nt++)
      acc[mt][nt] = (f32x4){bb[nt], bb[nt], bb[nt], bb[nt]};
#pragma unroll
  for (int kb = 0; kb < 4; kb++) {
    short8 am0 = *(const short8*)(feat + (r0 + mrow) * 128 + kb * 32 + kg * 8);
    short8 am1 = *(const short8*)(feat + (r0 + 16 + mrow) * 128 + kb * 32 + kg * 8);
    acc[0][0] = __builtin_amdgcn_mfma_f32_16x16x32_bf16(am0, bfr[0][kb], acc[0][0], 0, 0, 0);
    acc[0][1] = __builtin_amdgcn_mfma_f32_16x16x32_bf16(am0, bfr[1][kb], acc[0][1], 0, 0, 0);
    acc[1][0] = __builtin_amdgcn_mfma_f32_16x16x32_bf16(am1, bfr[0][kb], acc[1][0], 0, 0, 0);
    acc[1][1] = __builtin_amdgcn_mfma_f32_16x16x32_bf16(am1, bfr[1][kb], acc[1][1], 0, 0, 0);
  }
#pragma unroll
  for (int mt = 0; mt < 2; mt++) {
#pragma unroll
    for (int nt = 0; nt < 2; nt++) {
      int col = nt * 16 + mrow;
      if (col < T_) {
#pragma unroll
        for (int q = 0; q < 4; q++) {
          int row = mt * 16 + kg * 4 + q;
          logits[(r0 + row) * T_ + col] = acc[mt][nt][q];
        }
      }
    }
  }
}

// ---------------- K4: CRF forward; i-sum split across wave halves -------------
// Lane j (j<25) owns output tag j with E-cols i=0..12; lane j+32 owns the
// partner partial i=13..24 (pad term qS[25]=0). One shfl_xor(32) combines ->
// fma chain per step halves vs the 25-term version.
__global__ __launch_bounds__(64) void k_crf(const float* __restrict__ logits,
                                            const float* __restrict__ trans,
                                            float* __restrict__ totals) {
  int j = threadIdx.x;
  int b = blockIdx.x;
  int half = j >> 5;                   // 0: lower, 1: upper (partner)
  int jj = j & 31;                     // output tag this lane serves
  bool act = (half == 0) && (jj < T_); // owns prev/q/output
  bool pact = (jj < T_);               // participates in the partial sum
  int bo = half ? 13 : 0;              // i-range base: 0..12 / 13..25(pad)
  float Evec[13];
#pragma unroll
  for (int k = 0; k < 13; k++) {
    int i = bo + k;
    Evec[k] = (pact && i < T_) ? __expf(trans[i * T_ + jj]) : 0.f;
  }
  __shared__ __align__(16) float qS[32];
  if (j >= T_ && j < 32) qS[j] = 0.f;  // zero-pad q[25..31] once (incl. qS[25])
  float tstop = act ? trans[jj * T_ + STOP_] : 0.f;
  float prev = act ? 0.f : -INFINITY;
  const float* lg = logits + (size_t)b * S_ * T_;
  float ltn = act ? lg[jj] : 0.f;
  asm volatile("s_waitcnt lgkmcnt(0)" ::: "memory");
  for (int t = 0; t < S_; t++) {
    float lt = ltn;
    if (t + 1 < S_) ltn = act ? lg[(size_t)(t + 1) * T_ + jj] : 0.f;
    float m = __builtin_bit_cast(float,
        __builtin_amdgcn_readfirstlane(__builtin_bit_cast(int, prev)));
    float q = __expf(prev - m);
    if (act) qS[j] = q;
    asm volatile("s_waitcnt lgkmcnt(0)" ::: "memory");
    // partial sum over this half's i-range (4 indep chains of <=4)
    float s0 = qS[bo + 0] * Evec[0];
    float s1 = qS[bo + 1] * Evec[1];
    float s2 = qS[bo + 2] * Evec[2];
    float s3 = qS[bo + 3] * Evec[3];
    s0 += qS[bo + 4] * Evec[4];
    s1 += qS[bo + 5] * Evec[5];
    s2 += qS[bo + 6] * Evec[6];
    s3 += qS[bo + 7] * Evec[7];
    s0 += qS[bo + 8] * Evec[8];
    s1 += qS[bo + 9] * Evec[9];
    s2 += qS[bo + 10] * Evec[10];
    s3 += qS[bo + 11] * Evec[11];
    s0 += qS[bo + 12] * Evec[12];
    float sp = (s0 + s1) + (s2 + s3);
    float s = sp + __shfl_xor(sp, 32, 64);   // combine halves
    prev = lt + m + __logf(s);               // s==0 -> -inf (fp32 underflow)
    if (!act) prev = -INFINITY;
  }
  float v = prev + tstop;                    // non-act lanes: -inf
  float m = v;
#pragma unroll
  for (int off = 32; off > 0; off >>= 1)
    m = fmaxf(m, __shfl_xor(m, off, 64));
  float e = __expf(v - m);
#pragma unroll
  for (int off = 32; off > 0; off >>= 1)
    e += __shfl_xor(e, off, 64);
  if (j == 0) totals[b] = m + __logf(e);
}

// ---------------- K5: gold path score per b ----------------------------------
__global__ __launch_bounds__(256) void k_real(const float* __restrict__ logits,
                                              const int* __restrict__ tags,
                                              const float* __restrict__ trans,
                                              float* __restrict__ reals) {
  __shared__ float red[256];
  int b = blockIdx.x;
  float acc = 0.f;
  for (int s = threadIdx.x; s < S_; s += 256) {
    int tg = tags[(size_t)b * S_ + s];
    int pv = (s == 0) ? START_ : tags[(size_t)b * S_ + s - 1];
    acc += logits[((size_t)b * S_ + s) * T_ + tg] + trans[pv * T_ + tg];
  }
  red[threadIdx.x] = acc;
  __syncthreads();
  for (int off = 128; off > 0; off >>= 1) {
    if (threadIdx.x < off) red[threadIdx.x] += red[threadIdx.x + off];
    __syncthreads();
  }
  if (threadIdx.x == 0)
    reals[b] = red[0] + trans[tags[(size_t)b * S_ + S_ - 1] * T_ + STOP_];
}

// ---------------- K6: out = sum_b totals - reals -----------------------------
__global__ __launch_bounds__(256) void k_final(const float* __restrict__ totals,
                                               const float* __restrict__ reals,
                                               float* __restrict__ out) {
  __shared__ float red[256];
  float acc = 0.f;
  for (int b = threadIdx.x; b < B_; b += 256) acc += totals[b] - reals[b];
  red[threadIdx.x] = acc;
  __syncthreads();
  for (int off = 128; off > 0; off >>= 1) {
    if (threadIdx.x < off) red[threadIdx.x] += red[threadIdx.x + off];
    __syncthreads();
  }
  if (threadIdx.x == 0) out[0] = red[0];
}

// ws: Pf 5,120,000 | Pb 5,120,000 | feat(bf16) 67,108,864 | logits 26,214,400
//   | WoutP 8,192 | totals 2,048 | reals 2,048
extern "C" void kernel_launch(void* const* d_in, const int* in_sizes, int n_in,
                              void* d_out, int out_size, void* d_ws, size_t ws_size,
                              hipStream_t stream) {
  const int*   sentences = (const int*)d_in[0];
  const int*   tags  = (const int*)d_in[1];
  const float* embed = (const float*)d_in[2];
  const float* Wih_f = (const float*)d_in[3];
  const float* Whh_f = (const float*)d_in[4];
  const float* bih_f = (const float*)d_in[5];
  const float* bhh_f = (const float*)d_in[6];
  const float* Wih_b = (const float*)d_in[7];
  const float* Whh_b = (const float*)d_in[8];
  const float* bih_b = (const float*)d_in[9];
  const float* bhh_b = (const float*)d_in[10];
  const float* h0    = (const float*)d_in[11];
  const float* c0    = (const float*)d_in[12];
  const float* Wout  = (const float*)d_in[13];
  const float* bout  = (const float*)d_in[14];
  const float* trans = (const float*)d_in[15];

  char* ws = (char*)d_ws;
  float* Pf = (float*)(ws);
  float* Pb = (float*)(ws + 5120000);
  __hip_bfloat16* feat = (__hip_bfloat16*)(ws + 10240000);
  float* logits = (float*)(ws + 10240000 + 67108864);
  __hip_bfloat16* WoutP = (__hip_bfloat16*)(ws + 10240000 + 67108864 + 26214400);
  float* totals = (float*)(ws + 10240000 + 67108864 + 26214400 + 8192);
  float* reals  = totals + B_;
  float* out    = (float*)d_out;

  k_proj<<<dim3(313, 2), 256, 0, stream>>>(embed, Wih_f, Wih_b, Pf, Pb);
  k_prep<<<16, 256, 0, stream>>>(Wout, WoutP);
  k_lstm<<<1024, 64, 0, stream>>>(sentences, Pf, Pb, Whh_f, Whh_b,
                                  bih_f, bhh_f, bih_b, bhh_b, h0, c0, feat);
  k_logits<<<2048, 256, 0, stream>>>(feat, WoutP, bout, logits);
  k_crf<<<512, 64, 0, stream>>>(logits, trans, totals);
  k_real<<<512, 256, 0, stream>>>(logits, tags, trans, reals);
  k_final<<<1, 256, 0, stream>>>(totals, reals, out);
}